// Round 1
// baseline (92.390 us; speedup 1.0000x reference)
//
#include <hip/hip_runtime.h>
#include <math.h>

#define B_  2048
#define H_  256
#define IN_ 64

typedef __attribute__((ext_vector_type(8))) short bf8_t;   // 8 x bf16 (4 VGPR)
typedef __attribute__((ext_vector_type(4))) short s4_t;
typedef __attribute__((ext_vector_type(4))) float f4_t;

#define MFMA_BF16(a, b, c) __builtin_amdgcn_mfma_f32_16x16x32_bf16((a), (b), (c), 0, 0, 0)

__device__ __forceinline__ short f2bf(float f) {         // rne
  union { float f; unsigned u; } v; v.f = f;
  unsigned u = v.u + 0x7fffu + ((v.u >> 16) & 1u);
  return (short)(u >> 16);
}
__device__ __forceinline__ float bf2f(short s) {
  union { unsigned u; float f; } v; v.u = ((unsigned)(unsigned short)s) << 16;
  return v.f;
}

// Pre-split weights in MFMA B-fragment layout: element j of fragment
// [(g*NKS+ks)*64+lane] is W[c][k], c = g*16 + (lane&15), k = ks*32 + (lane>>4)*8 + j.
__device__ __align__(16) short g_whf[2][65536];   // [hi/lo] 256x256
__device__ __align__(16) short g_wof[2][65536];   // [hi/lo] 256x256
__device__ __align__(16) short g_wxf[2][16384];   // [hi/lo] 256x64

__global__ void prep_frag(const float* __restrict__ wh, const float* __restrict__ wo,
                          const float* __restrict__ wx) {
  int tid = blockIdx.x * 256 + threadIdx.x;       // 72*256 = 18432
  const float* W; short* Dh; short* Dl; int ld, ksh, o8;
  if (tid < 8192)       { W = wh; Dh = g_whf[0]; Dl = g_whf[1]; ld = 256; ksh = 3; o8 = tid; }
  else if (tid < 16384) { W = wo; Dh = g_wof[0]; Dl = g_wof[1]; ld = 256; ksh = 3; o8 = tid - 8192; }
  else if (tid < 18432) { W = wx; Dh = g_wxf[0]; Dl = g_wxf[1]; ld = 64;  ksh = 1; o8 = tid - 16384; }
  else return;
  int lane = o8 & 63;
  int gks = o8 >> 6;
  int g = gks >> ksh, ks = gks & ((1 << ksh) - 1);
  int c = g * 16 + (lane & 15);
  int k0 = ks * 32 + ((lane >> 4) & 3) * 8;
  const float* p = W + (size_t)c * ld + k0;
  bf8_t hi, lo;
#pragma unroll
  for (int j = 0; j < 8; ++j) {
    float f = p[j];
    short h = f2bf(f);
    hi[j] = h; lo[j] = f2bf(f - bf2f(h));
  }
  *reinterpret_cast<bf8_t*>(Dh + (size_t)o8 * 8) = hi;
  *reinterpret_cast<bf8_t*>(Dl + (size_t)o8 * 8) = lo;
}

// A-fragment load from LDS (uses ln/lq from scope)
#define LDA(AH, ks) (*reinterpret_cast<const bf8_t*>(&AH[ln][(ks) * 32 + lq * 8]))
// Streamed weight-fragment load from global frag table (uses wv/lane from scope)
#define LDW(BASE, NKS, ks) \
  (*reinterpret_cast<const bf8_t*>((BASE) + ((size_t)(wv * (NKS) + (ks)) * 64 + lane) * 8))

// 3-term split GEMM, resident WH array + STREAMED WL (term-split partials: chains of NK)
#define GEMM3RS(A0, AH, AL, WH, WLBASE, NK) do {                                \
  f4_t q_ = {0.f,0.f,0.f,0.f}, p_ = {0.f,0.f,0.f,0.f};                          \
  _Pragma("unroll")                                                             \
  for (int ks = 0; ks < (NK); ++ks) {                                           \
    bf8_t ah = LDA(AH, ks);                                                     \
    bf8_t al = LDA(AL, ks);                                                     \
    bf8_t wl = LDW(WLBASE, NK, ks);                                             \
    A0 = MFMA_BF16(ah, WH[ks], A0);                                             \
    q_ = MFMA_BF16(ah, wl, q_);                                                 \
    p_ = MFMA_BF16(al, WH[ks], p_);                                             \
  }                                                                             \
  A0 = A0 + (q_ + p_); } while (0)

// 3-term split GEMM, BOTH weights streamed (for the small wx fragments)
#define GEMM3SS(A0, AH, AL, WHB, WLB, NK) do {                                  \
  f4_t q_ = {0.f,0.f,0.f,0.f}, p_ = {0.f,0.f,0.f,0.f};                          \
  _Pragma("unroll")                                                             \
  for (int ks = 0; ks < (NK); ++ks) {                                           \
    bf8_t ah = LDA(AH, ks);                                                     \
    bf8_t al = LDA(AL, ks);                                                     \
    bf8_t wh_ = LDW(WHB, NK, ks);                                               \
    bf8_t wl_ = LDW(WLB, NK, ks);                                               \
    A0 = MFMA_BF16(ah, wh_, A0);                                                \
    q_ = MFMA_BF16(ah, wl_, q_);                                                \
    p_ = MFMA_BF16(al, wh_, p_);                                                \
  }                                                                             \
  A0 = A0 + (q_ + p_); } while (0)

// 2-term split GEMM (A-hi/lo x resident W-hi), term-split partials
#define GEMM2R(A0, AH, AL, WH, NK) do {                                         \
  f4_t q_ = {0.f,0.f,0.f,0.f};                                                  \
  _Pragma("unroll")                                                             \
  for (int ks = 0; ks < (NK); ++ks) {                                           \
    bf8_t ah = LDA(AH, ks);                                                     \
    bf8_t al = LDA(AL, ks);                                                     \
    A0 = MFMA_BF16(ah, WH[ks], A0);                                             \
    q_ = MFMA_BF16(al, WH[ks], q_);                                             \
  }                                                                             \
  A0 = A0 + q_; } while (0)

// 1-term GEMM for the chain, 4-way ks partial split (dependent chains of 2)
#define GEMM1R(A0, AH, WH, NK) do {                                             \
  f4_t q_ = {0.f,0.f,0.f,0.f}, p_ = {0.f,0.f,0.f,0.f}, s_ = {0.f,0.f,0.f,0.f}; \
  _Pragma("unroll")                                                             \
  for (int ks = 0; ks < (NK); ++ks) {                                           \
    bf8_t ah = LDA(AH, ks);                                                     \
    if ((ks & 3) == 0)      A0 = MFMA_BF16(ah, WH[ks], A0);                     \
    else if ((ks & 3) == 1) q_ = MFMA_BF16(ah, WH[ks], q_);                     \
    else if ((ks & 3) == 2) p_ = MFMA_BF16(ah, WH[ks], p_);                     \
    else                    s_ = MFMA_BF16(ah, WH[ks], s_);                     \
  }                                                                             \
  A0 = (A0 + q_) + (p_ + s_); } while (0)

// 16 waves x 16 output cols each (was 8 x 32): per-wave persistent weight
// registers drop from 192 to 64 VGPR, lo-split weights are streamed at use,
// so the kernel fits the 128-VGPR cap of __launch_bounds__(1024,4) and runs
// 4 waves/SIMD (2x the latency-hiding TLP of the 512-thread version).
__global__ __launch_bounds__(1024, 4) void jacde_mfma(
    const float* __restrict__ h_g, const float* __restrict__ x_g,
    const float* __restrict__ xd_g, const float* __restrict__ wx,
    const float* __restrict__ wh, const float* __restrict__ b0,
    const float* __restrict__ b1, float* __restrict__ out) {

  __shared__ short h_hi[16][264], h_lo[16][264];  // h staging; reused for u0 after stage 1
  __shared__ short x_hi[16][72],  x_lo[16][72];
  __shared__ short xd_hi[16][72], xd_lo[16][72];
  __shared__ short u_hi[16][264], u_lo[16][264];
  __shared__ short v_hi[16][264];
  __shared__ float l1_t[16][264];                 // l1; later aliased as bf16 curr buffer
  __shared__ int   fix_cnt;
  __shared__ int   fix_list[64];

  short (*vb)[264] = reinterpret_cast<short (*)[264]>(l1_t);  // bf16 alias of l1_t

  const int tid  = threadIdx.x;
  const int wv   = tid >> 6;        // 0..15
  const int lane = tid & 63;
  const int ln   = lane & 15;       // A row / C col-within-tile
  const int lq   = lane >> 4;       // quad
  const int r0   = blockIdx.x * 16; // batch-row base
  const int cb   = wv * 16;         // wave's output-column base (single 16-col group)

  if (tid == 0) fix_cnt = 0;

  // ---- stage activations to split-bf16 LDS (1024 threads: 1 f4 chunk each) ----
  {
    int r = tid >> 6, k4 = (tid & 63) * 4;
    f4_t v = *reinterpret_cast<const f4_t*>(h_g + (size_t)(r0 + r) * H_ + k4);
    s4_t shv, slv;
#pragma unroll
    for (int j = 0; j < 4; ++j) { short h = f2bf(v[j]); shv[j] = h; slv[j] = f2bf(v[j] - bf2f(h)); }
    *reinterpret_cast<s4_t*>(&h_hi[r][k4]) = shv;
    *reinterpret_cast<s4_t*>(&h_lo[r][k4]) = slv;
  }
  if (tid < 512) {
    int t2 = tid & 255;
    const float* src = (tid < 256) ? x_g : xd_g;
    short (*dh)[72] = (tid < 256) ? x_hi : xd_hi;
    short (*dl)[72] = (tid < 256) ? x_lo : xd_lo;
    int r = t2 >> 4, k4 = (t2 & 15) * 4;
    f4_t v = *reinterpret_cast<const f4_t*>(src + (size_t)(r0 + r) * IN_ + k4);
    s4_t shv, slv;
#pragma unroll
    for (int j = 0; j < 4; ++j) { short h = f2bf(v[j]); shv[j] = h; slv[j] = f2bf(v[j] - bf2f(h)); }
    *reinterpret_cast<s4_t*>(&dh[r][k4]) = shv;
    *reinterpret_cast<s4_t*>(&dl[r][k4]) = slv;
  }

  // ---- persistent weight fragments (hi only; lo parts streamed at use) ----
  bf8_t whf[8], wof[8];
  f4_t acc, sacc;
  float dre[4], dta[4], hd[4];
  float bv1;

  // ---- stage 1: l1 = x@wx^T + h@wh^T + b0 (3-term);  s = xdot@wx^T (3-term) ----
  {
#pragma unroll
    for (int ks = 0; ks < 8; ++ks) whf[ks] = LDW(g_whf[0], 8, ks);
    __syncthreads();   // activations staged

    float bv0 = b0[cb + ln];
    acc = (f4_t){bv0, bv0, bv0, bv0};
    GEMM3RS(acc, h_hi, h_lo, whf, g_whf[1], 8);
    GEMM3SS(acc, x_hi, x_lo, g_wxf[0], g_wxf[1], 2);
    sacc = (f4_t){0.f, 0.f, 0.f, 0.f};
    GEMM3SS(sacc, xd_hi, xd_lo, g_wxf[0], g_wxf[1], 2);
#pragma unroll
    for (int r = 0; r < 4; ++r) {   // C/D: col=lane&15, row=quad*4+reg [m89]
      l1_t[lq * 4 + r][cb + ln] = acc[r];
      // merged fixup scan: owner wave flags its own near-zero l1 values
      if (fabsf(acc[r]) < 1e-4f) {
        int idx = atomicAdd(&fix_cnt, 1);
        if (idx < 64) fix_list[idx] = ((lq * 4 + r) << 8) | (cb + ln);
      }
    }
  }

  // ---- hoisted loads: wout-hi frags + b1 (latency overlaps fixup + gate) ----
  bv1 = b1[cb + ln];
#pragma unroll
  for (int ks = 0; ks < 8; ++ks) wof[ks] = LDW(g_wof[0], 8, ks);
  __syncthreads();

  // ---- fp64 fixup of near-zero l1 (hard relu gate must match fp64 anchor).
  //      fix_cnt is block-uniform post-barrier -> uniform branch, barrier only
  //      when work exists (common case skips it entirely) ----
  {
    int nfix = min(fix_cnt, 64);
    if (nfix) {
      for (int e = wv; e < nfix; e += 16) {
        int rc = fix_list[e];
        int r = rc >> 8, c = rc & 255;
        const float* hrow = h_g + (size_t)(r0 + r) * H_;
        const float* wrow = wh + (size_t)c * H_;
        double sum = (double)hrow[lane]       * (double)wrow[lane]
                   + (double)hrow[lane + 64]  * (double)wrow[lane + 64]
                   + (double)hrow[lane + 128] * (double)wrow[lane + 128]
                   + (double)hrow[lane + 192] * (double)wrow[lane + 192]
                   + (double)x_g[(size_t)(r0 + r) * IN_ + lane] * (double)wx[(size_t)c * IN_ + lane];
#pragma unroll
        for (int m = 32; m; m >>= 1) sum += __shfl_xor(sum, m);
        if (lane == 0) l1_t[r][c] = (float)(sum + (double)b0[c]);
      }
      __syncthreads();
    }
  }

  // ---- gate (owner-wave local): relu split -> u bufs; u0 = dre*s -> h bufs (dead) ----
#pragma unroll
  for (int r = 0; r < 4; ++r) {
    int row = lq * 4 + r;
    float l1v = l1_t[row][cb + ln];
    dre[r] = (l1v > 0.f) ? 1.f : 0.f;
    float rv = l1v > 0.f ? l1v : 0.f;
    short rh = f2bf(rv);
    u_hi[row][cb + ln] = rh;  u_lo[row][cb + ln] = f2bf(rv - bf2f(rh));
    float u0 = dre[r] * sacc[r];
    short uh = f2bf(u0);
    h_hi[row][cb + ln] = uh;  h_lo[row][cb + ln] = f2bf(u0 - bf2f(uh));
  }
  __syncthreads();

  // ---- fused: lout = relu@wout^T + b1 (3-term, wol streamed) -> dtanh;
  //      jx-pre = u0@wout^T (2-term); two independent MFMA chains, no barrier ----
  {
    acc = (f4_t){bv1, bv1, bv1, bv1};
    GEMM3RS(acc, u_hi, u_lo, wof, g_wof[1], 8);
    sacc = (f4_t){0.f, 0.f, 0.f, 0.f};
    GEMM2R(sacc, h_hi, h_lo, wof, 8);
#pragma unroll
    for (int r = 0; r < 4; ++r) {
      float t = tanhf(acc[r]);
      dta[r] = 1.f - t * t;
      int row = lq * 4 + r;
      float v = dta[r] * sacc[r];   // jx = curr_term_0 = h_dot init
      hd[r] = v;
      vb[row][cb + ln] = f2bf(v);   // curr -> l1_t alias (u bufs still being read)
    }
  }
  __syncthreads();

  // ---- 7x 1-term chain (series truncation: J^8 term dropped — terms decay
  //      geometrically; prior session R6 showed chain tail < 1 output ULP) ----
  const short (*vsrc)[264] = vb;    // iter 0 reads the alias; later iters read v_hi
  for (int it = 0; it < 7; ++it) {
    acc = (f4_t){0.f, 0.f, 0.f, 0.f};
    GEMM1R(acc, vsrc, whf, 8);
#pragma unroll
    for (int r = 0; r < 4; ++r)
      u_hi[lq * 4 + r][cb + ln] = f2bf(dre[r] * acc[r]);
    __syncthreads();

    acc = (f4_t){0.f, 0.f, 0.f, 0.f};
    GEMM1R(acc, u_hi, wof, 8);
#pragma unroll
    for (int r = 0; r < 4; ++r) {
      float v = dta[r] * acc[r];
      hd[r] += v;
      if (it < 6) v_hi[lq * 4 + r][cb + ln] = f2bf(v);
    }
    vsrc = v_hi;
    if (it < 6) __syncthreads();   // last iteration writes nothing cross-wave
  }

  // ---- epilogue: fp32 out ----
#pragma unroll
  for (int r = 0; r < 4; ++r)
    out[(size_t)(r0 + lq * 4 + r) * H_ + cb + ln] = hd[r];
}

extern "C" void kernel_launch(void* const* d_in, const int* in_sizes, int n_in,
                              void* d_out, int out_size, void* d_ws, size_t ws_size,
                              hipStream_t stream) {
  const float* h_g  = (const float*)d_in[0];
  const float* x_g  = (const float*)d_in[1];
  const float* xd_g = (const float*)d_in[2];
  const float* wx   = (const float*)d_in[3];
  const float* wh   = (const float*)d_in[4];
  const float* wo   = (const float*)d_in[5];
  const float* b0   = (const float*)d_in[6];
  const float* b1   = (const float*)d_in[7];
  prep_frag<<<dim3(72), dim3(256), 0, stream>>>(wh, wo, wx);
  jacde_mfma<<<dim3(B_ / 16), dim3(1024), 0, stream>>>(
      h_g, x_g, xd_g, wx, wh, b0, b1, (float*)d_out);
}